// Round 8
// baseline (65.216 us; speedup 1.0000x reference)
//
#include <hip/hip_runtime.h>

#define H  4096
#define W  8192
#define KH 3
#define KW 3
#define HO (H - KH + 1)   // 4094
#define WO (W - KW + 1)   // 8190
#define CPT 4             // output cols per thread
#define RPS 4             // output rows per strip
#define SPB 8             // strips per block band
#define BAND (RPS * SPB)  // 32 output rows per block
#define BLK 256

typedef float vfloat4 __attribute__((ext_vector_type(4)));
typedef float vfloat2 __attribute__((ext_vector_type(2)));

__global__ __launch_bounds__(BLK, 4) void ConvLayer_4140348473931_kernel(
    const float* __restrict__ X, const float* __restrict__ Wt,
    const float* __restrict__ Bias, float* __restrict__ Out)
{
    const int tid   = threadIdx.x;
    const int c0    = blockIdx.x * (BLK * CPT) + tid * CPT;  // multiple of 4
    const int rbase = blockIdx.y * BAND;
    // last thread (c0=8188) would read cols 8192/8193; clamp the float2 to W-2.
    // Wrong lanes feed only outputs >= WO which are masked.
    const int cext  = min(c0 + 4, W - 2);

    float w[9];
#pragma unroll
    for (int i = 0; i < 9; ++i) w[i] = Wt[i];
    const float bias = Bias[0];

    float x[6][6];      // rolling window: 6 input rows x 6 cols
    float preA[4][6];   // prefetch ping
    float preB[4][6];   // prefetch pong

    // nt loads: mark input evict-first so it never thrashes the MALL; each
    // replay then refills sequentially instead of with random L3-hole misses.
#define LOADROW(rr, dst)                                                     \
    do {                                                                     \
        int _r = (rr); if (_r > H - 1) _r = H - 1;                           \
        const float* _row = X + (size_t)_r * W;                              \
        vfloat4 _v  = __builtin_nontemporal_load(                            \
            reinterpret_cast<const vfloat4*>(_row + c0));                    \
        vfloat2 _v2 = __builtin_nontemporal_load(                            \
            reinterpret_cast<const vfloat2*>(_row + cext));                  \
        (dst)[0] = _v.x;  (dst)[1] = _v.y;  (dst)[2] = _v.z;                 \
        (dst)[3] = _v.w;  (dst)[4] = _v2.x; (dst)[5] = _v2.y;                \
    } while (0)

    // prefetch for strip t loads its 4 NEW rows: rbase + t*RPS + 2 .. +5
#define PREFETCH(t, buf)                                                     \
    do {                                                                     \
        if ((t) < SPB) {                                                     \
            _Pragma("unroll")                                                \
            for (int _ir = 0; _ir < RPS; ++_ir)                              \
                LOADROW(rbase + (t) * RPS + 2 + _ir, (buf)[_ir]);            \
        }                                                                    \
    } while (0)

#define COMPUTE_STORE(s)                                                     \
    do {                                                                     \
        float acc[RPS][CPT];                                                 \
        _Pragma("unroll")                                                    \
        for (int _i = 0; _i < RPS; ++_i) {                                   \
            _Pragma("unroll")                                                \
            for (int _j = 0; _j < CPT; ++_j) {                               \
                float _s = bias;                                             \
                _Pragma("unroll")                                            \
                for (int _kh = 0; _kh < KH; ++_kh)                           \
                    _Pragma("unroll")                                        \
                    for (int _kw = 0; _kw < KW; ++_kw)                       \
                        _s = fmaf(w[_kh * 3 + _kw], x[_i + _kh][_j + _kw], _s); \
                acc[_i][_j] = _s;                                            \
            }                                                                \
        }                                                                    \
        const int _r0 = rbase + (s) * RPS;                                   \
        const bool _full = (c0 + CPT <= WO);                                 \
        _Pragma("unroll")                                                    \
        for (int _i = 0; _i < RPS; ++_i) {                                   \
            int _r = _r0 + _i;                                               \
            if (_r < HO) {                                                   \
                float* _orow = Out + (size_t)_r * WO + c0;                   \
                *reinterpret_cast<float2*>(_orow) = make_float2(acc[_i][0], acc[_i][1]); \
                if (_full)                                                   \
                    *reinterpret_cast<float2*>(_orow + 2) = make_float2(acc[_i][2], acc[_i][3]); \
            }                                                                \
        }                                                                    \
    } while (0)

#define SHIFT_FROM(buf)                                                      \
    do {                                                                     \
        _Pragma("unroll")                                                    \
        for (int _j = 0; _j < 6; ++_j) { x[0][_j] = x[4][_j]; x[1][_j] = x[5][_j]; } \
        _Pragma("unroll")                                                    \
        for (int _ir = 0; _ir < RPS; ++_ir)                                  \
            _Pragma("unroll")                                                \
            for (int _j = 0; _j < 6; ++_j) x[2 + _ir][_j] = (buf)[_ir][_j];  \
    } while (0)

    // pipeline fill: strip 0 window + strip 1's new rows
#pragma unroll
    for (int ir = 0; ir < 6; ++ir) LOADROW(rbase + ir, x[ir]);
    PREFETCH(1, preA);

    // main loop, strips in pairs so preA/preB roles are static (no runtime idx)
#pragma unroll
    for (int p = 0; p < SPB / 2; ++p) {
        const int s0 = 2 * p;
        PREFETCH(s0 + 2, preB);       // 2-deep: issue strip s0+2 loads now
        COMPUTE_STORE(s0);
        SHIFT_FROM(preA);             // waits on preA (issued 2 strips ago)

        PREFETCH(s0 + 3, preA);       // issue strip s0+3 loads
        COMPUTE_STORE(s0 + 1);
        if (s0 + 2 < SPB) SHIFT_FROM(preB);
    }

#undef LOADROW
#undef PREFETCH
#undef COMPUTE_STORE
#undef SHIFT_FROM
}

extern "C" void kernel_launch(void* const* d_in, const int* in_sizes, int n_in,
                              void* d_out, int out_size, void* d_ws, size_t ws_size,
                              hipStream_t stream) {
    const float* X    = (const float*)d_in[0];
    const float* Wt   = (const float*)d_in[1];
    const float* Bias = (const float*)d_in[2];
    float* Out        = (float*)d_out;

    dim3 block(BLK);
    dim3 grid((WO + BLK * CPT - 1) / (BLK * CPT),   // 8  -> XCD = bx (column stripe per XCD)
              (HO + BAND - 1) / BAND);              // 128
    ConvLayer_4140348473931_kernel<<<grid, block, 0, stream>>>(X, Wt, Bias, Out);
}

// Round 9
// 53.069 us; speedup vs baseline: 1.2289x; 1.2289x over previous
//
#include <hip/hip_runtime.h>

#define H   4096
#define W   8192
#define HO  4094          // H-2
#define WO  8190          // W-2
#define TWI 256           // staged input cols per tile (one gll dwordx4 sweep)
#define TWO 252           // output cols per tile (63 segs x 4)
#define TH  16            // output rows per tile
#define IH  18            // staged input rows per tile
#define TPB 8             // row-tiles per block (consecutive band)
#define BLK 256

typedef __attribute__((address_space(3))) void       lds_void;
typedef __attribute__((address_space(1))) const void glob_void;

__global__ __launch_bounds__(BLK) void ConvLayer_4140348473931_kernel(
    const float* __restrict__ X, const float* __restrict__ Wt,
    const float* __restrict__ Bias, float* __restrict__ Out)
{
    __shared__ float bufA[IH][TWI];   // 18 KB
    __shared__ float bufB[IH][TWI];   // 18 KB  -> 36.9 KB total, 4 blocks/CU

    const int tid  = threadIdx.x;
    const int lane = tid & 63;
    const int wav  = tid >> 6;

    const int Cbase = blockIdx.x * TWO;            // 33 column tiles
    const int Rblk  = blockIdx.y * (TPB * TH);     // 32 bands of 128 rows

    // per-lane global column for staging; clamp keeps the 16B load in-row
    // (duplicated cols feed only outputs >= WO which are masked on store)
    const int gcol = min(Cbase + 4 * lane, W - 4);

    float w[9];
#pragma unroll
    for (int i = 0; i < 9; ++i) w[i] = Wt[i];
    const float bias = Bias[0];

    const int lr = wav * 4;          // local output row base (4 rows/thread)
    const int lc = lane * 4;         // local col base (seg 63 = compute-only garbage)
    const int oc = Cbase + lc;

    // ---- stage one tile: wave w DMAs rows w, w+4, ... via global_load_lds ----
    // LDS dest is wave-uniform base + lane*16 (linear row); global src per-lane.
#define STAGE(BUF, R0)                                                        \
    do {                                                                      \
        _Pragma("unroll")                                                     \
        for (int k = 0; k < 5; ++k) {                                         \
            const int rr = wav + 4 * k;                                       \
            if (rr < IH) {                                                    \
                int gr = (R0) + rr; if (gr > H - 1) gr = H - 1;               \
                const float* src = X + (size_t)gr * W + gcol;                 \
                __builtin_amdgcn_global_load_lds(                             \
                    (glob_void*)src, (lds_void*)&(BUF)[rr][0], 16, 0, 0);     \
            }                                                                 \
        }                                                                     \
    } while (0)

    // counted waits: waves 0,1 keep 5 next-tile loads in flight, waves 2,3 keep 4
#define WAITN()                                                               \
    do { if (wav < 2) asm volatile("s_waitcnt vmcnt(5)" ::: "memory");        \
         else         asm volatile("s_waitcnt vmcnt(4)" ::: "memory"); } while (0)
#define WAIT0() asm volatile("s_waitcnt vmcnt(0)" ::: "memory")
#define FENCE() asm volatile("" ::: "memory")
#define BAR()   do { __builtin_amdgcn_s_barrier(); FENCE(); } while (0)

    // ---- compute 4x4 outputs/thread from an LDS tile, then store ----
#define CSTORE(BUF, R0)                                                       \
    do {                                                                      \
        float acc[4][4];                                                      \
        _Pragma("unroll") for (int i = 0; i < 4; ++i)                         \
        _Pragma("unroll") for (int j = 0; j < 4; ++j) acc[i][j] = bias;       \
        _Pragma("unroll")                                                     \
        for (int ir = 0; ir < 6; ++ir) {                                      \
            float4 a4 = *reinterpret_cast<const float4*>(&(BUF)[lr + ir][lc]);\
            float2 b2 = *reinterpret_cast<const float2*>(&(BUF)[lr + ir][lc + 4]); \
            const float xw[6] = {a4.x, a4.y, a4.z, a4.w, b2.x, b2.y};         \
            _Pragma("unroll")                                                 \
            for (int i = 0; i < 4; ++i) {                                     \
                const int kh = ir - i;                                        \
                if (kh >= 0 && kh < 3) {                                      \
                    _Pragma("unroll")                                         \
                    for (int j = 0; j < 4; ++j) {                             \
                        float s = acc[i][j];                                  \
                        s = fmaf(w[kh * 3 + 0], xw[j + 0], s);                \
                        s = fmaf(w[kh * 3 + 1], xw[j + 1], s);                \
                        s = fmaf(w[kh * 3 + 2], xw[j + 2], s);                \
                        acc[i][j] = s;                                        \
                    }                                                         \
                }                                                             \
            }                                                                 \
        }                                                                     \
        if (lane < 63) {                                                      \
            _Pragma("unroll")                                                 \
            for (int i = 0; i < 4; ++i) {                                     \
                const int r = (R0) + lr + i;                                  \
                if (r < HO) {                                                 \
                    float* orow = Out + (size_t)r * WO + oc;                  \
                    if (oc + 2 <= WO)                                         \
                        *reinterpret_cast<float2*>(orow) = make_float2(acc[i][0], acc[i][1]); \
                    if (oc + 4 <= WO)                                         \
                        *reinterpret_cast<float2*>(orow + 2) = make_float2(acc[i][2], acc[i][3]); \
                }                                                             \
            }                                                                 \
        }                                                                     \
    } while (0)

    // ---- software pipeline: stage t+1 while computing t; vmcnt never 0 mid-loop ----
    STAGE(bufA, Rblk);
#pragma unroll
    for (int t = 0; t < TPB; t += 2) {
        const int R0 = Rblk + t * TH;

        if (t + 1 < TPB) { STAGE(bufB, R0 + TH); WAITN(); } else { WAIT0(); }
        BAR();                       // bufA ready for everyone
        CSTORE(bufA, R0);
        FENCE(); BAR();              // all reads of bufA done before overwrite

        if (t + 2 < TPB) { STAGE(bufA, R0 + 2 * TH); WAITN(); } else { WAIT0(); }
        BAR();                       // bufB ready
        CSTORE(bufB, R0 + TH);
        FENCE(); BAR();              // all reads of bufB done before overwrite
    }

#undef STAGE
#undef WAITN
#undef WAIT0
#undef FENCE
#undef BAR
#undef CSTORE
}

extern "C" void kernel_launch(void* const* d_in, const int* in_sizes, int n_in,
                              void* d_out, int out_size, void* d_ws, size_t ws_size,
                              hipStream_t stream) {
    const float* X    = (const float*)d_in[0];
    const float* Wt   = (const float*)d_in[1];
    const float* Bias = (const float*)d_in[2];
    float* Out        = (float*)d_out;

    dim3 block(BLK);
    dim3 grid((WO + TWO - 1) / TWO,          // 33 column tiles (last is half-width work)
              (HO + TPB * TH - 1) / (TPB * TH));  // 32 bands -> 1056 blocks, 4/CU (LDS-capped)
    ConvLayer_4140348473931_kernel<<<grid, block, 0, stream>>>(X, Wt, Bias, Out);
}

// Round 10
// 51.175 us; speedup vs baseline: 1.2744x; 1.0370x over previous
//
#include <hip/hip_runtime.h>

#define H    4096
#define W    8192
#define HO   4094          // H-2
#define WO   8190          // W-2
#define TWI  256           // staged input cols per tile
#define TWO  252           // output cols per tile (63 segs x 4)
#define TH   16            // output rows per tile
#define IH   18            // staged input rows per tile
#define NCT  33            // ceil(WO/TWO) column tiles
#define NBT  256           // ceil(HO/TH) row bands
#define NT   (NCT * NBT)   // 8448 tiles
#define NBLK 512           // grid-stride blocks: phase window = ~16 full-width bands
#define BLK  256

typedef __attribute__((address_space(3))) void       lds_void;
typedef __attribute__((address_space(1))) const void glob_void;

__global__ __launch_bounds__(BLK) void ConvLayer_4140348473931_kernel(
    const float* __restrict__ X, const float* __restrict__ Wt,
    const float* __restrict__ Bias, float* __restrict__ Out)
{
    __shared__ float bufA[IH][TWI];   // 18 KB
    __shared__ float bufB[IH][TWI];   // 18 KB

    const int tid  = threadIdx.x;
    const int lane = tid & 63;
    const int wav  = tid >> 6;

    float w[9];
#pragma unroll
    for (int i = 0; i < 9; ++i) w[i] = Wt[i];
    const float bias = Bias[0];

    const int lr = wav * 4;          // local output row base (4 rows/thread)
    const int lc = lane * 4;         // local col base (seg 63 = compute-only garbage)

    // ---- stage tile T into BUFP: wave w DMAs rows w, w+4, ... (5/5/4/4) ----
#define STAGE(BUFP, T)                                                        \
    do {                                                                      \
        const int _band = (T) / NCT;                                          \
        const int _ct   = (T) - _band * NCT;                                  \
        const int _R0   = _band * TH;                                         \
        const int _gc   = min(_ct * TWO + 4 * lane, W - 4);                   \
        _Pragma("unroll")                                                     \
        for (int k = 0; k < 5; ++k) {                                         \
            const int rr = wav + 4 * k;                                       \
            if (rr < IH) {                                                    \
                int gr = _R0 + rr; if (gr > H - 1) gr = H - 1;                \
                const float* src = X + (size_t)gr * W + _gc;                  \
                __builtin_amdgcn_global_load_lds(                             \
                    (glob_void*)src, (lds_void*)&(BUFP)[rr][0], 16, 0, 0);    \
            }                                                                 \
        }                                                                     \
    } while (0)

    // ---- compute 4x4 outputs/thread from LDS tile T, then store ----
#define CSTORE(BUFP, T)                                                       \
    do {                                                                      \
        const int _band = (T) / NCT;                                          \
        const int _ct   = (T) - _band * NCT;                                  \
        const int _R0   = _band * TH;                                         \
        const int _oc   = _ct * TWO + lc;                                     \
        float acc[4][4];                                                      \
        _Pragma("unroll") for (int i = 0; i < 4; ++i)                         \
        _Pragma("unroll") for (int j = 0; j < 4; ++j) acc[i][j] = bias;       \
        _Pragma("unroll")                                                     \
        for (int ir = 0; ir < 6; ++ir) {                                      \
            float4 a4 = *reinterpret_cast<const float4*>(&(BUFP)[lr + ir][lc]); \
            float2 b2 = *reinterpret_cast<const float2*>(&(BUFP)[lr + ir][lc + 4]); \
            const float xw[6] = {a4.x, a4.y, a4.z, a4.w, b2.x, b2.y};         \
            _Pragma("unroll")                                                 \
            for (int i = 0; i < 4; ++i) {                                     \
                const int kh = ir - i;                                        \
                if (kh >= 0 && kh < 3) {                                      \
                    _Pragma("unroll")                                         \
                    for (int j = 0; j < 4; ++j) {                             \
                        float s = acc[i][j];                                  \
                        s = fmaf(w[kh * 3 + 0], xw[j + 0], s);                \
                        s = fmaf(w[kh * 3 + 1], xw[j + 1], s);                \
                        s = fmaf(w[kh * 3 + 2], xw[j + 2], s);                \
                        acc[i][j] = s;                                        \
                    }                                                         \
                }                                                             \
            }                                                                 \
        }                                                                     \
        if (lane < 63) {                                                      \
            _Pragma("unroll")                                                 \
            for (int i = 0; i < 4; ++i) {                                     \
                const int r = _R0 + lr + i;                                   \
                if (r < HO) {                                                 \
                    float* orow = Out + (size_t)r * WO + _oc;                 \
                    if (_oc + 2 <= WO)                                        \
                        *reinterpret_cast<float2*>(orow) = make_float2(acc[i][0], acc[i][1]); \
                    if (_oc + 4 <= WO)                                        \
                        *reinterpret_cast<float2*>(orow + 2) = make_float2(acc[i][2], acc[i][3]); \
                }                                                             \
            }                                                                 \
        }                                                                     \
    } while (0)

    // ---- grid-stride over tiles, col-fastest: device sweeps dense row bands ----
    int T = (int)blockIdx.x;
    STAGE(bufA, T);
    int cur = 0;
    while (true) {
        const int Tn = T + NBLK;
        float (*bc)[TWI] = cur ? bufB : bufA;   // holds tile T (loads awaited below)
        float (*bn)[TWI] = cur ? bufA : bufB;   // receives tile Tn

        if (Tn < NT) {
            STAGE(bn, Tn);
            // wait for tile T's loads; keep tile Tn's 5 (or 4) in flight
            if (wav < 2) asm volatile("s_waitcnt vmcnt(5)" ::: "memory");
            else         asm volatile("s_waitcnt vmcnt(4)" ::: "memory");
        } else {
            asm volatile("s_waitcnt vmcnt(0)" ::: "memory");
        }
        __builtin_amdgcn_s_barrier();           // tile T visible to all waves

        CSTORE(bc, T);

        asm volatile("" ::: "memory");
        __builtin_amdgcn_s_barrier();           // all reads done before overwrite

        if (Tn >= NT) break;
        T = Tn; cur ^= 1;
    }

#undef STAGE
#undef CSTORE
}

extern "C" void kernel_launch(void* const* d_in, const int* in_sizes, int n_in,
                              void* d_out, int out_size, void* d_ws, size_t ws_size,
                              hipStream_t stream) {
    const float* X    = (const float*)d_in[0];
    const float* Wt   = (const float*)d_in[1];
    const float* Bias = (const float*)d_in[2];
    float* Out        = (float*)d_out;

    dim3 block(BLK);
    dim3 grid(NBLK);   // 512 grid-stride blocks, 2/CU; dense full-width sweep
    ConvLayer_4140348473931_kernel<<<grid, block, 0, stream>>>(X, Wt, Bias, Out);
}

// Round 11
// 47.306 us; speedup vs baseline: 1.3786x; 1.0818x over previous
//
#include <hip/hip_runtime.h>

#define H  4096
#define W  8192
#define KH 3
#define KW 3
#define HO (H - KH + 1)   // 4094
#define WO (W - KW + 1)   // 8190
#define CPT 4             // output cols per thread
#define RPS 4             // output rows per strip
#define SPB 8             // strips per block band
#define BAND (RPS * SPB)  // 32 output rows per block
#define BLK 256

__global__ __launch_bounds__(BLK, 4) void ConvLayer_4140348473931_kernel(
    const float* __restrict__ X, const float* __restrict__ Wt,
    const float* __restrict__ Bias, float* __restrict__ Out)
{
    const int tid   = threadIdx.x;
    const int c0    = blockIdx.x * (BLK * CPT) + tid * CPT;  // multiple of 4
    const int rbase = blockIdx.y * BAND;
    // last thread (c0=8188) would read cols 8192/8193; clamp the float2 to W-2.
    // Wrong lanes feed only outputs >= WO which are masked.
    const int cext  = min(c0 + 4, W - 2);

    float w[9];
#pragma unroll
    for (int i = 0; i < 9; ++i) w[i] = Wt[i];
    const float bias = Bias[0];

    float x[6][6];      // rolling window: 6 input rows x 6 cols
    float preA[4][6];   // prefetch ping
    float preB[4][6];   // prefetch pong

#define LOADROW(rr, dst)                                                     \
    do {                                                                     \
        int _r = (rr); if (_r > H - 1) _r = H - 1;                           \
        const float* _row = X + (size_t)_r * W;                              \
        float4 _v  = *reinterpret_cast<const float4*>(_row + c0);            \
        float2 _v2 = *reinterpret_cast<const float2*>(_row + cext);          \
        (dst)[0] = _v.x;  (dst)[1] = _v.y;  (dst)[2] = _v.z;                 \
        (dst)[3] = _v.w;  (dst)[4] = _v2.x; (dst)[5] = _v2.y;                \
    } while (0)

    // prefetch for strip t loads its 4 NEW rows: rbase + t*RPS + 2 .. +5
#define PREFETCH(t, buf)                                                     \
    do {                                                                     \
        if ((t) < SPB) {                                                     \
            _Pragma("unroll")                                                \
            for (int _ir = 0; _ir < RPS; ++_ir)                              \
                LOADROW(rbase + (t) * RPS + 2 + _ir, (buf)[_ir]);            \
        }                                                                    \
    } while (0)

#define COMPUTE_STORE(s)                                                     \
    do {                                                                     \
        float acc[RPS][CPT];                                                 \
        _Pragma("unroll")                                                    \
        for (int _i = 0; _i < RPS; ++_i) {                                   \
            _Pragma("unroll")                                                \
            for (int _j = 0; _j < CPT; ++_j) {                               \
                float _s = bias;                                             \
                _Pragma("unroll")                                            \
                for (int _kh = 0; _kh < KH; ++_kh)                           \
                    _Pragma("unroll")                                        \
                    for (int _kw = 0; _kw < KW; ++_kw)                       \
                        _s = fmaf(w[_kh * 3 + _kw], x[_i + _kh][_j + _kw], _s); \
                acc[_i][_j] = _s;                                            \
            }                                                                \
        }                                                                    \
        const int _r0 = rbase + (s) * RPS;                                   \
        const bool _full = (c0 + CPT <= WO);                                 \
        _Pragma("unroll")                                                    \
        for (int _i = 0; _i < RPS; ++_i) {                                   \
            int _r = _r0 + _i;                                               \
            if (_r < HO) {                                                   \
                float* _orow = Out + (size_t)_r * WO + c0;                   \
                *reinterpret_cast<float2*>(_orow) = make_float2(acc[_i][0], acc[_i][1]); \
                if (_full)                                                   \
                    *reinterpret_cast<float2*>(_orow + 2) = make_float2(acc[_i][2], acc[_i][3]); \
            }                                                                \
        }                                                                    \
    } while (0)

#define SHIFT_FROM(buf)                                                      \
    do {                                                                     \
        _Pragma("unroll")                                                    \
        for (int _j = 0; _j < 6; ++_j) { x[0][_j] = x[4][_j]; x[1][_j] = x[5][_j]; } \
        _Pragma("unroll")                                                    \
        for (int _ir = 0; _ir < RPS; ++_ir)                                  \
            _Pragma("unroll")                                                \
            for (int _j = 0; _j < 6; ++_j) x[2 + _ir][_j] = (buf)[_ir][_j];  \
    } while (0)

    // pipeline fill: strip 0 window + strip 1's new rows
#pragma unroll
    for (int ir = 0; ir < 6; ++ir) LOADROW(rbase + ir, x[ir]);
    PREFETCH(1, preA);

    // main loop, strips in pairs so preA/preB roles are static (no runtime idx)
#pragma unroll
    for (int p = 0; p < SPB / 2; ++p) {
        const int s0 = 2 * p;
        PREFETCH(s0 + 2, preB);       // 2-deep: issue strip s0+2 loads now
        COMPUTE_STORE(s0);
        SHIFT_FROM(preA);             // waits on preA (issued 2 strips ago)

        PREFETCH(s0 + 3, preA);       // issue strip s0+3 loads
        COMPUTE_STORE(s0 + 1);
        if (s0 + 2 < SPB) SHIFT_FROM(preB);
    }

#undef LOADROW
#undef PREFETCH
#undef COMPUTE_STORE
#undef SHIFT_FROM
}

extern "C" void kernel_launch(void* const* d_in, const int* in_sizes, int n_in,
                              void* d_out, int out_size, void* d_ws, size_t ws_size,
                              hipStream_t stream) {
    const float* X    = (const float*)d_in[0];
    const float* Wt   = (const float*)d_in[1];
    const float* Bias = (const float*)d_in[2];
    float* Out        = (float*)d_out;

    dim3 block(BLK);
    dim3 grid((WO + BLK * CPT - 1) / (BLK * CPT),   // 8  -> XCD = bx (column stripe per XCD)
              (HO + BAND - 1) / BAND);              // 128
    ConvLayer_4140348473931_kernel<<<grid, block, 0, stream>>>(X, Wt, Bias, Out);
}